// Round 4
// baseline (570.216 us; speedup 1.0000x reference)
//
#include <hip/hip_runtime.h>
#include <math.h>

typedef __attribute__((ext_vector_type(4))) float f32x4;
typedef __attribute__((ext_vector_type(8))) short bf16x8;       // 8 bf16 in 4 VGPRs
typedef __attribute__((ext_vector_type(8))) unsigned short u16x8;
typedef __attribute__((ext_vector_type(4))) unsigned short u16x4;

#define FI4(p) (*reinterpret_cast<const float4*>(p))
#define FO4(p) (*reinterpret_cast<float4*>(p))

// ---------- bf16 split helpers (round-to-nearest-even) ----------
__device__ __forceinline__ unsigned short f2bf(float x) {
  unsigned u = __float_as_uint(x);
  u += 0x7FFFu + ((u >> 16) & 1u);
  return (unsigned short)(u >> 16);
}
__device__ __forceinline__ float bf2f(unsigned short h) {
  return __uint_as_float(((unsigned)h) << 16);
}

// Fragment-order swizzled offset for logical row-major [rows][1024] matrices.
// Tile = 128 rows x 32 k, stored [tm][kt][s][lane][8]:
//   s = sub-tile of 16 rows, lane = ((k>>3)&3)*16 + (row&15), j = k&7.
// A linear LDS copy of one 4096-elem tile then yields conflict-free
// ds_read_b128 MFMA fragments (lane -> consecutive 16B), matching the
// 16x16x32 A/B operand layout: row=lane&15, k=(lane>>4)*8+j.
__device__ __forceinline__ size_t swz_off(int row, int kg) {   // kg = k/8
  int tm = row >> 7;
  int kt = kg >> 2;
  int s  = (row & 127) >> 4;
  int lane = ((kg & 3) << 4) | (row & 15);
  return (((size_t)(tm * 32 + kt)) << 12) + ((size_t)s << 9) + ((size_t)lane << 3);
}

__device__ __forceinline__ void gload16(const ushort* g, ushort* l) {
  __builtin_amdgcn_global_load_lds((const __attribute__((address_space(1))) void*)(g),
                                   (__attribute__((address_space(3))) void*)(l), 16, 0, 0);
}

// split 4 floats -> hi/lo bf16 quads at LDS offset off (ushort units, 8B aligned)
__device__ __forceinline__ void sw4(ushort* hbuf, ushort* lbuf, int off,
                                    float a, float b, float c, float d) {
  float v[4] = {a, b, c, d};
  u16x4 hv, lv;
  #pragma unroll
  for (int e = 0; e < 4; ++e) {
    unsigned short h = f2bf(v[e]);
    hv[e] = h;
    lv[e] = f2bf(v[e] - bf2f(h));
  }
  *reinterpret_cast<u16x4*>(hbuf + off) = hv;
  *reinterpret_cast<u16x4*>(lbuf + off) = lv;
}

// ---------- preprocessing task bodies ----------
__device__ __forceinline__ void split_body(
    const float* __restrict__ in, ushort* __restrict__ hi, ushort* __restrict__ lo, int gid)
{
  int row = gid >> 7, kg = gid & 127;
  const float* p = in + ((size_t)row << 10) + (kg << 3);
  float4 a = FI4(p), b = FI4(p + 4);
  float v[8] = {a.x, a.y, a.z, a.w, b.x, b.y, b.z, b.w};
  u16x8 hv, lv;
  #pragma unroll
  for (int j = 0; j < 8; ++j) {
    unsigned short h = f2bf(v[j]);
    hv[j] = h;
    lv[j] = f2bf(v[j] - bf2f(h));
  }
  size_t o = swz_off(row, kg);
  *reinterpret_cast<u16x8*>(hi + o) = hv;
  *reinterpret_cast<u16x8*>(lo + o) = lv;
}

__device__ __forceinline__ void tsplit_body(
    const float* __restrict__ W, ushort* __restrict__ hi, ushort* __restrict__ lo, int gid)
{
  int n = gid & 1023, kg = gid >> 10;
  float v[8];
  #pragma unroll
  for (int j = 0; j < 8; ++j)
    v[j] = W[((size_t)(kg * 8 + j) << 10) + n];   // coalesced across lanes per j
  u16x8 hv, lv;
  #pragma unroll
  for (int j = 0; j < 8; ++j) {
    unsigned short h = f2bf(v[j]);
    hv[j] = h;
    lv[j] = f2bf(v[j] - bf2f(h));
  }
  size_t o = swz_off(n, kg);
  *reinterpret_cast<u16x8*>(hi + o) = hv;
  *reinterpret_cast<u16x8*>(lo + o) = lv;
}

__device__ __forceinline__ void build_r_body(
    ushort* __restrict__ hi, ushort* __restrict__ lo, int gid)
{
  int p = gid >> 7, kg = gid & 127;
  float pos = (float)(p - 1023);
  u16x8 hv, lv;
  #pragma unroll
  for (int j = 0; j < 8; ++j) {
    int c = kg * 8 + j;
    float ex = (float)(c & ~1) * (1.0f / 1024.0f);
    float invf = exp2f(-ex * 13.2877123795494f);   // 10000^-ex
    float ang = pos * invf;
    float val = (c & 1) ? cosf(ang) : sinf(ang);
    unsigned short h = f2bf(val);
    hv[j] = h;
    lv[j] = f2bf(val - bf2f(h));
  }
  size_t o = swz_off(p, kg);
  *reinterpret_cast<u16x8*>(hi + o) = hv;
  *reinterpret_cast<u16x8*>(lo + o) = lv;
}

// one launch: y = task {0:X-split 1:Y-split 2:Wo-split 3..6:W-transpose-splits 7:R-table}
__global__ __launch_bounds__(256) void pre_k(
    const float* X, const float* Y, const float* Wo,
    const float* Wq, const float* We, const float* Wv, const float* Wr,
    ushort* Xh, ushort* Xl, ushort* Yh, ushort* Yl, ushort* Woh, ushort* Wol,
    ushort* WqTh, ushort* WqTl, ushort* WeTh, ushort* WeTl,
    ushort* WvTh, ushort* WvTl, ushort* WrTh, ushort* WrTl,
    ushort* Rh, ushort* Rl)
{
  const int gid = blockIdx.x * 256 + threadIdx.x;
  switch (blockIdx.y) {
    case 0: split_body(X, Xh, Xl, gid); break;                       // 2048*128 = full grid
    case 1: split_body(Y, Yh, Yl, gid); break;
    case 2: if (gid < 1024*128) split_body(Wo, Woh, Wol, gid); break;
    case 3: if (gid < 1024*128) tsplit_body(Wq, WqTh, WqTl, gid); break;
    case 4: if (gid < 1024*128) tsplit_body(We, WeTh, WeTl, gid); break;
    case 5: if (gid < 1024*128) tsplit_body(Wv, WvTh, WvTl, gid); break;
    case 6: if (gid < 1024*128) tsplit_body(Wr, WrTh, WrTl, gid); break;
    default: if (gid < 2047*128) build_r_body(Rh, Rl, gid); break;
  }
}

// O-split after attention (separate: depends on attn output)
__global__ __launch_bounds__(256) void split_swz_k(
    const float* __restrict__ in, ushort* __restrict__ hi, ushort* __restrict__ lo, int rows)
{
  int gid = blockIdx.x * 256 + threadIdx.x;
  if (gid >= rows * 128) return;
  split_body(in, hi, lo, gid);
}

// ---------- split-bf16 MFMA GEMM core: C[M,1024] = A @ Bt^T ----------
// A,B given as swizzled hi/lo bf16. 128x128 tile, 4 waves (2x2), BK=32.
// 3 MFMA passes (hh + hl + lh) ~ f32 accuracy (err ~1e-5 rel).
template<int EPI>
__device__ __forceinline__ void gemm_core(
    ushort lds[4][4096],
    const ushort* __restrict__ Ah, const ushort* __restrict__ Al,
    const ushort* __restrict__ Bh, const ushort* __restrict__ Bl,
    float* __restrict__ C, int M,
    const float* __restrict__ bias, const float* __restrict__ resid)
{
  const int tid = threadIdx.x;
  const int w = tid >> 6, lane = tid & 63;
  const int tm = blockIdx.y, tn = blockIdx.x;
  const int wm = w >> 1, wn = w & 1;

  f32x4 acc[4][4];
  #pragma unroll
  for (int i = 0; i < 4; ++i)
    #pragma unroll
    for (int j = 0; j < 4; ++j)
      acc[i][j] = (f32x4){0.f, 0.f, 0.f, 0.f};

  // wave w stages one of the four 8KB tiles (Ah/Al/Bh/Bl) per K-step
  const ushort* mysrc;
  if      (w == 0) mysrc = Ah + (((size_t)tm * 32) << 12);
  else if (w == 1) mysrc = Al + (((size_t)tm * 32) << 12);
  else if (w == 2) mysrc = Bh + (((size_t)tn * 32) << 12);
  else             mysrc = Bl + (((size_t)tn * 32) << 12);
  mysrc += lane * 8;
  ushort* mylds = &lds[w][0];

  for (int kt = 0; kt < 32; ++kt) {
    #pragma unroll
    for (int c = 0; c < 8; ++c)
      gload16(mysrc + c * 512, mylds + c * 512);   // 1KB per call per wave
    mysrc += 4096;
    __syncthreads();   // compiler drains vmcnt before s_barrier

    bf16x8 ah[4], al[4], bh4[4], bl4[4];
    #pragma unroll
    for (int i = 0; i < 4; ++i) {
      ah[i]  = *reinterpret_cast<const bf16x8*>(&lds[0][(wm*4 + i)*512 + lane*8]);
      al[i]  = *reinterpret_cast<const bf16x8*>(&lds[1][(wm*4 + i)*512 + lane*8]);
      bh4[i] = *reinterpret_cast<const bf16x8*>(&lds[2][(wn*4 + i)*512 + lane*8]);
      bl4[i] = *reinterpret_cast<const bf16x8*>(&lds[3][(wn*4 + i)*512 + lane*8]);
    }
    #pragma unroll
    for (int i = 0; i < 4; ++i)
      #pragma unroll
      for (int j = 0; j < 4; ++j) {
        acc[i][j] = __builtin_amdgcn_mfma_f32_16x16x32_bf16(ah[i], bh4[j], acc[i][j], 0, 0, 0);
        acc[i][j] = __builtin_amdgcn_mfma_f32_16x16x32_bf16(ah[i], bl4[j], acc[i][j], 0, 0, 0);
        acc[i][j] = __builtin_amdgcn_mfma_f32_16x16x32_bf16(al[i], bh4[j], acc[i][j], 0, 0, 0);
      }
    __syncthreads();
  }

  // C/D layout (verified m89/m91): col = lane&15, row = (lane>>4)*4 + reg
  const int r0 = tm*128 + wm*64 + ((lane >> 4) << 2);
  const int c0 = tn*128 + wn*64 + (lane & 15);
  #pragma unroll
  for (int i = 0; i < 4; ++i)
    #pragma unroll
    for (int r = 0; r < 4; ++r) {
      const int row = r0 + i*16 + r;
      if (row < M) {
        #pragma unroll
        for (int j = 0; j < 4; ++j) {
          const int col = c0 + j*16;
          float v = acc[i][j][r];
          if (EPI) v += bias[col] + resid[((size_t)row << 10) + col];
          C[((size_t)row << 10) + col] = v;
        }
      }
    }
}

// fused q/k/v/Qm projections: grid (8, 16, 4) -> 512 workgroups, full machine
__global__ __launch_bounds__(256, 2) void gemm4_k(
    const ushort* Xh, const ushort* Xl, const ushort* Yh, const ushort* Yl,
    const ushort* Rh, const ushort* Rl,
    const ushort* WqTh, const ushort* WqTl, const ushort* WeTh, const ushort* WeTl,
    const ushort* WvTh, const ushort* WvTl, const ushort* WrTh, const ushort* WrTl,
    float* qb, float* kb, float* vb, float* Qm)
{
  __shared__ ushort lds[4][4096];
  const int z = blockIdx.z;
  const ushort *Ah, *Al, *Bh, *Bl; float* C; int M = 2048;
  if (z == 0)      { Ah = Xh; Al = Xl; Bh = WqTh; Bl = WqTl; C = qb; }
  else if (z == 1) { Ah = Yh; Al = Yl; Bh = WeTh; Bl = WeTl; C = kb; }
  else if (z == 2) { Ah = Yh; Al = Yl; Bh = WvTh; Bl = WvTl; C = vb; }
  else             { Ah = Rh; Al = Rl; Bh = WrTh; Bl = WrTl; C = Qm; M = 2047; }
  gemm_core<0>(lds, Ah, Al, Bh, Bl, C, M, nullptr, nullptr);
}

// out-projection with bias + residual epilogue: Z = O @ Wo^T + b + X
__global__ __launch_bounds__(256, 2) void gemm_epi_k(
    const ushort* Oh, const ushort* Ol, const ushort* Wh, const ushort* Wl,
    float* Z, const float* bias, const float* resid)
{
  __shared__ ushort lds[4][4096];
  gemm_core<1>(lds, Oh, Ol, Wh, Wl, Z, 2048, bias, resid);
}

// ---------------- Fused causal attention, hybrid MFMA S-phase ----------------
// Per block: one (n, head, 32-query tile). Logit (j<=i):
//   (q_i+cb)·k_j + (1 + (i==j)) * (q_i+pb)·Qmat[j-i+1023]
// S (32x64) and Srel (32x96) computed by split-bf16 MFMA into LDS;
// softmax + PV kept in the verified f32 per-thread structure.
__global__ __launch_bounds__(256) void attn_k(
    const float* __restrict__ qg, const float* __restrict__ kg,
    const float* __restrict__ vg, const float* __restrict__ Qm,
    const float* __restrict__ cb, const float* __restrict__ pb,
    float* __restrict__ Og)
{
  // fragment-order buffers: [sub][lane][8] ushorts; sub = rowblock*2 + kblock
  __shared__ ushort Qch[2048], Qcl[2048], Qph[2048], Qpl[2048];  // q+cb, q+pb (32x64)
  __shared__ ushort Kh[4096], Kl[4096];                          // K tile (64x64)
  __shared__ ushort Gh[6144], Gl[6144];                          // Qm window (96x64)
  __shared__ float Sex[32][68];    // S exchange; later P exchange
  __shared__ float Srl[32][100];   // Srel exchange (cols 0..95)

  const int tid = threadIdx.x;
  const int tx = tid & 15, ty = tid >> 4;
  const int blk = blockIdx.x;
  const int qt = 31 - (blk & 31);       // long diagonals dispatched first
  const int nh = blk >> 5;
  const int hh = nh & 15;
  const int n = nh >> 4;
  const int i0 = qt << 5;
  const int iA = ty << 1;               // 2 query rows per thread (softmax/PV phase)
  const size_t base = (size_t)n * (1024 * 1024) + (hh << 6);

  // staging decomposition: thread = (jr = row-group 0..15, kg4 = float4-along-k 0..15)
  const int kg4 = tid & 15;
  const int jr  = tid >> 4;
  const int skb = kg4 >> 3;             // kblock (k = kg4*4 -> k>>5)
  const int lhi = (kg4 >> 1) & 3;       // (k&31)>>3
  const int elo = (kg4 & 1) << 2;       // k&7 base (0 or 4)

  // ---- stage q fragments (q+cb and q+pb), once ----
  {
    float4 c4 = FI4(&cb[(hh << 6) + (kg4 << 2)]);
    float4 p4 = FI4(&pb[(hh << 6) + (kg4 << 2)]);
    #pragma unroll
    for (int r = 0; r < 2; ++r) {
      int row = jr + (r << 4);
      float4 v = FI4(&qg[base + (size_t)(i0 + row) * 1024 + (kg4 << 2)]);
      int off = ((((row >> 4) << 1) | skb) << 9) + (((lhi << 4) | (row & 15)) << 3) + elo;
      sw4(Qch, Qcl, off, v.x + c4.x, v.y + c4.y, v.z + c4.z, v.w + c4.w);
      sw4(Qph, Qpl, off, v.x + p4.x, v.y + p4.y, v.z + p4.z, v.w + p4.w);
    }
  }

  // MFMA-phase wave decomposition: wave w -> A rowblock (w&1), colblocks 5*(w>>1)..+4
  const int w = tid >> 6, lane = tid & 63;
  const int rb = w & 1;
  const int c0w = (w >> 1) * 5;
  const int rloc = (rb << 4) + ((lane >> 4) << 2);  // C row base (m89 layout)
  const int cloc = lane & 15;                        // C col

  float m_run[2] = {-1e30f, -1e30f};
  float l_run[2] = {0.f, 0.f};
  float acc[2][4] = {{0.f,0.f,0.f,0.f},{0.f,0.f,0.f,0.f}};
  const int jt_max = (i0 + 31) >> 6;

  for (int jt = 0; jt <= jt_max; ++jt) {
    const int j0 = jt << 6;
    __syncthreads();   // B1: prev-tile PV reads of Sex + frag reads of K/G done

    // ---- stage K tile (64 keys x 64 feat) ----
    #pragma unroll
    for (int r = 0; r < 4; ++r) {
      int row = jr + (r << 4);
      float4 v = FI4(&kg[base + (size_t)(j0 + row) * 1024 + (kg4 << 2)]);
      int off = ((((row >> 4) << 1) | skb) << 9) + (((lhi << 4) | (row & 15)) << 3) + elo;
      sw4(Kh, Kl, off, v.x, v.y, v.z, v.w);
    }
    // ---- stage G = Qm window rows m0..m0+95 ----
    const int m0 = j0 - i0 + 992;   // in [0, 960]
    #pragma unroll
    for (int r = 0; r < 6; ++r) {
      int row = jr + (r << 4);
      float4 v = FI4(&Qm[(size_t)(m0 + row) * 1024 + (hh << 6) + (kg4 << 2)]);
      int off = ((((row >> 4) << 1) | skb) << 9) + (((lhi << 4) | (row & 15)) << 3) + elo;
      sw4(Gh, Gl, off, v.x, v.y, v.z, v.w);
    }
    __syncthreads();   // B2: stage complete

    // ---- MFMA: 5 C-subtiles per wave (3-pass split bf16, K=64 via 2 kblocks) ----
    f32x4 sacc[5];
    #pragma unroll
    for (int s = 0; s < 5; ++s) sacc[s] = (f32x4){0.f, 0.f, 0.f, 0.f};
    #pragma unroll
    for (int s = 0; s < 5; ++s) {
      const int c = c0w + s;
      const bool isK = (c < 4);
      const ushort* Ahp = isK ? Qch : Qph;
      const ushort* Alp = isK ? Qcl : Qpl;
      const ushort* Bhp = isK ? Kh : Gh;
      const ushort* Blp = isK ? Kl : Gl;
      const int cb_ = isK ? c : (c - 4);
      #pragma unroll
      for (int kb_ = 0; kb_ < 2; ++kb_) {
        const int aoff = ((((rb << 1) | kb_) << 9) + (lane << 3));
        const int boff = ((((cb_ << 1) | kb_) << 9) + (lane << 3));
        bf16x8 a_h = *reinterpret_cast<const bf16x8*>(Ahp + aoff);
        bf16x8 a_l = *reinterpret_cast<const bf16x8*>(Alp + aoff);
        bf16x8 b_h = *reinterpret_cast<const bf16x8*>(Bhp + boff);
        bf16x8 b_l = *reinterpret_cast<const bf16x8*>(Blp + boff);
        sacc[s] = __builtin_amdgcn_mfma_f32_16x16x32_bf16(a_h, b_h, sacc[s], 0, 0, 0);
        sacc[s] = __builtin_amdgcn_mfma_f32_16x16x32_bf16(a_h, b_l, sacc[s], 0, 0, 0);
        sacc[s] = __builtin_amdgcn_mfma_f32_16x16x32_bf16(a_l, b_h, sacc[s], 0, 0, 0);
      }
    }
    // ---- C fragments -> LDS exchange ----
    #pragma unroll
    for (int s = 0; s < 5; ++s) {
      const int c = c0w + s;
      #pragma unroll
      for (int reg = 0; reg < 4; ++reg) {
        if (c < 4) Sex[rloc + reg][(c << 4) + cloc] = sacc[s][reg];
        else       Srl[rloc + reg][((c - 4) << 4) + cloc] = sacc[s][reg];
      }
    }
    __syncthreads();   // B3: S/Srel ready

    // ---- softmax (per-thread layout, unchanged structure) ----
    float p[2][4];
    #pragma unroll
    for (int di = 0; di < 2; ++di) {
      const int gi = i0 + iA + di;
      float mx = -1e30f;
      #pragma unroll
      for (int dj = 0; dj < 4; ++dj) {
        const int jl = tx + (dj << 4);
        const int gj = j0 + jl;
        float val = Sex[iA + di][jl]
                  + ((gj == gi) ? 2.0f : 1.0f) * Srl[iA + di][jl - iA - di + 31];
        val = (gj <= gi) ? val : -1e30f;
        p[di][dj] = val;
        mx = fmaxf(mx, val);
      }
      mx = fmaxf(mx, __shfl_xor(mx, 1));
      mx = fmaxf(mx, __shfl_xor(mx, 2));
      mx = fmaxf(mx, __shfl_xor(mx, 4));
      mx = fmaxf(mx, __shfl_xor(mx, 8));
      const float mnew = fmaxf(m_run[di], mx);
      const float sc = __expf(m_run[di] - mnew);
      float ps = 0.f;
      #pragma unroll
      for (int dj = 0; dj < 4; ++dj) {
        p[di][dj] = __expf(p[di][dj] - mnew);
        ps += p[di][dj];
      }
      ps += __shfl_xor(ps, 1);
      ps += __shfl_xor(ps, 2);
      ps += __shfl_xor(ps, 4);
      ps += __shfl_xor(ps, 8);
      l_run[di] = l_run[di] * sc + ps;
      m_run[di] = mnew;
      #pragma unroll
      for (int c2 = 0; c2 < 4; ++c2) acc[di][c2] *= sc;
    }
    __syncthreads();   // B4: all S/Srel reads done
    #pragma unroll
    for (int di = 0; di < 2; ++di)
      #pragma unroll
      for (int dj = 0; dj < 4; ++dj)
        Sex[iA + di][tx + (dj << 4)] = p[di][dj];   // P overlays S exchange
    __syncthreads();   // B5: P ready

    // ---- PV (f32, V streamed via L1/L2) ----
    const float* vrow = vg + base + (size_t)j0 * 1024 + (tx << 2);
    #pragma unroll
    for (int jj = 0; jj < 64; jj += 4) {
      float4 p0 = FI4(&Sex[iA][jj]);
      float4 p1 = FI4(&Sex[iA + 1][jj]);
      float pp0[4] = {p0.x, p0.y, p0.z, p0.w};
      float pp1[4] = {p1.x, p1.y, p1.z, p1.w};
      #pragma unroll
      for (int u = 0; u < 4; ++u) {
        float4 vv = FI4(vrow + (size_t)(jj + u) * 1024);
        acc[0][0] += pp0[u] * vv.x; acc[0][1] += pp0[u] * vv.y;
        acc[0][2] += pp0[u] * vv.z; acc[0][3] += pp0[u] * vv.w;
        acc[1][0] += pp1[u] * vv.x; acc[1][1] += pp1[u] * vv.y;
        acc[1][2] += pp1[u] * vv.z; acc[1][3] += pp1[u] * vv.w;
      }
    }
  }

  #pragma unroll
  for (int di = 0; di < 2; ++di) {
    const int gi = i0 + iA + di;
    const float inv = 1.0f / l_run[di];
    float4 o = make_float4(acc[di][0]*inv, acc[di][1]*inv,
                           acc[di][2]*inv, acc[di][3]*inv);
    FO4(&Og[base + (size_t)gi * 1024 + (tx << 2)]) = o;
  }
}

// ---------------- LayerNorm over rows of Z ----------------
__global__ __launch_bounds__(256) void ln_k(
    const float* __restrict__ Z, const float* __restrict__ g,
    const float* __restrict__ b, float* __restrict__ out)
{
  __shared__ float red[8];
  const int row = blockIdx.x;
  const int tid = threadIdx.x;
  const float* zr = Z + (size_t)row * 1024;
  float4 z = FI4(&zr[tid << 2]);
  float s = z.x + z.y + z.z + z.w;
  s += __shfl_xor(s, 32); s += __shfl_xor(s, 16); s += __shfl_xor(s, 8);
  s += __shfl_xor(s, 4);  s += __shfl_xor(s, 2);  s += __shfl_xor(s, 1);
  if ((tid & 63) == 0) red[tid >> 6] = s;
  __syncthreads();
  const float mu = (red[0] + red[1] + red[2] + red[3]) * (1.0f / 1024.0f);
  float4 d = make_float4(z.x - mu, z.y - mu, z.z - mu, z.w - mu);
  float sq = d.x*d.x + d.y*d.y + d.z*d.z + d.w*d.w;
  sq += __shfl_xor(sq, 32); sq += __shfl_xor(sq, 16); sq += __shfl_xor(sq, 8);
  sq += __shfl_xor(sq, 4);  sq += __shfl_xor(sq, 2);  sq += __shfl_xor(sq, 1);
  if ((tid & 63) == 0) red[4 + (tid >> 6)] = sq;
  __syncthreads();
  const float var = (red[4] + red[5] + red[6] + red[7]) * (1.0f / 1024.0f);
  const float inv = rsqrtf(var + 1e-5f);
  float4 gg = FI4(&g[tid << 2]);
  float4 bb = FI4(&b[tid << 2]);
  float4 o = make_float4(d.x*inv*gg.x + bb.x, d.y*inv*gg.y + bb.y,
                         d.z*inv*gg.z + bb.z, d.w*inv*gg.w + bb.w);
  FO4(&out[(size_t)row * 1024 + (tid << 2)]) = o;
}

extern "C" void kernel_launch(void* const* d_in, const int* in_sizes, int n_in,
                              void* d_out, int out_size, void* d_ws, size_t ws_size,
                              hipStream_t stream)
{
  const float* X   = (const float*)d_in[0];
  const float* Y   = (const float*)d_in[1];
  // d_in[2] = mask (causal), d_in[3] = h (16) — implied by structure
  const float* Wq  = (const float*)d_in[4];
  const float* We  = (const float*)d_in[5];
  const float* Wv  = (const float*)d_in[6];
  const float* Wr  = (const float*)d_in[7];
  const float* cb  = (const float*)d_in[8];
  const float* pb  = (const float*)d_in[9];
  const float* Wo  = (const float*)d_in[10];
  const float* Wob = (const float*)d_in[11];
  const float* lng = (const float*)d_in[12];
  const float* lnb = (const float*)d_in[13];
  float* out = (float*)d_out;
  char* base = (char*)d_ws;

  const size_t MB = 1u << 20;
  // 76 MB total, with sequential-lifetime aliasing
  float*  qb   = (float*)(base + 0*MB);
  float*  kb   = (float*)(base + 8*MB);
  float*  vb   = (float*)(base + 16*MB);
  float*  Qm   = (float*)(base + 24*MB);
  ushort* Xh   = (ushort*)(base + 32*MB);   // -> later Oh
  ushort* Xl   = (ushort*)(base + 36*MB);   // -> later Ol
  ushort* Yh   = (ushort*)(base + 40*MB);   // -> later Zb (f32, 8MB)
  ushort* Yl   = (ushort*)(base + 44*MB);
  ushort* Rh   = (ushort*)(base + 48*MB);   // -> later Ob (f32, 8MB)
  ushort* Rl   = (ushort*)(base + 52*MB);
  ushort* Oh   = Xh;
  ushort* Ol   = Xl;
  float*  Zb   = (float*)(base + 40*MB);
  float*  Ob   = (float*)(base + 48*MB);
  ushort* WqTh = (ushort*)(base + 56*MB);
  ushort* WqTl = (ushort*)(base + 58*MB);
  ushort* WeTh = (ushort*)(base + 60*MB);
  ushort* WeTl = (ushort*)(base + 62*MB);
  ushort* WvTh = (ushort*)(base + 64*MB);
  ushort* WvTl = (ushort*)(base + 66*MB);
  ushort* WrTh = (ushort*)(base + 68*MB);
  ushort* WrTl = (ushort*)(base + 70*MB);
  ushort* Woh  = (ushort*)(base + 72*MB);
  ushort* Wol  = (ushort*)(base + 74*MB);

  // ---- all preprocessing in ONE launch (splits / transposes / R table) ----
  pre_k<<<dim3(1024, 8), dim3(256), 0, stream>>>(
      X, Y, Wo, Wq, We, Wv, Wr,
      Xh, Xl, Yh, Yl, Woh, Wol,
      WqTh, WqTl, WeTh, WeTl, WvTh, WvTl, WrTh, WrTl,
      Rh, Rl);

  // ---- fused q/k/v/Qm projections on MFMA ----
  gemm4_k<<<dim3(8, 16, 4), dim3(256), 0, stream>>>(
      Xh, Xl, Yh, Yl, Rh, Rl,
      WqTh, WqTl, WeTh, WeTl, WvTh, WvTl, WrTh, WrTl,
      qb, kb, vb, Qm);

  // ---- fused attention (MFMA S-phase + f32 softmax/PV) ----
  attn_k<<<dim3(1024), dim3(256), 0, stream>>>(qb, kb, vb, Qm, cb, pb, Ob);

  // ---- out-projection on MFMA (+bias +residual), then LayerNorm ----
  split_swz_k<<<dim3(1024), dim3(256), 0, stream>>>(Ob, Oh, Ol, 2048);
  gemm_epi_k<<<dim3(8, 16), dim3(256), 0, stream>>>(Oh, Ol, Woh, Wol, Zb, Wob, X);
  ln_k<<<dim3(2048), dim3(256), 0, stream>>>(Zb, lng, lnb, out);
}

// Round 5
// 395.509 us; speedup vs baseline: 1.4417x; 1.4417x over previous
//
#include <hip/hip_runtime.h>
#include <math.h>

typedef __attribute__((ext_vector_type(4))) float f32x4;
typedef __attribute__((ext_vector_type(8))) short bf16x8;       // 8 bf16 in 4 VGPRs
typedef __attribute__((ext_vector_type(8))) unsigned short u16x8;

#define FI4(p) (*reinterpret_cast<const float4*>(p))
#define FO4(p) (*reinterpret_cast<float4*>(p))

// ---------- bf16 split helpers (round-to-nearest-even) ----------
__device__ __forceinline__ unsigned short f2bf(float x) {
  unsigned u = __float_as_uint(x);
  u += 0x7FFFu + ((u >> 16) & 1u);
  return (unsigned short)(u >> 16);
}
__device__ __forceinline__ float bf2f(unsigned short h) {
  return __uint_as_float(((unsigned)h) << 16);
}

// Fragment-order swizzled offset for logical row-major [rows][1024] matrices.
// Tile = 128 rows x 32 k, stored [tm][kt][s][lane][8]:
//   s = sub-tile of 16 rows, lane = ((k>>3)&3)*16 + (row&15), j = k&7.
__device__ __forceinline__ size_t swz_off(int row, int kg) {   // kg = k/8
  int tm = row >> 7;
  int kt = kg >> 2;
  int s  = (row & 127) >> 4;
  int lane = ((kg & 3) << 4) | (row & 15);
  return (((size_t)(tm * 32 + kt)) << 12) + ((size_t)s << 9) + ((size_t)lane << 3);
}

__device__ __forceinline__ void gload16(const ushort* g, ushort* l) {
  __builtin_amdgcn_global_load_lds((const __attribute__((address_space(1))) void*)(g),
                                   (__attribute__((address_space(3))) void*)(l), 16, 0, 0);
}

// ---------- preprocessing task bodies ----------
__device__ __forceinline__ void split_body(
    const float* __restrict__ in, ushort* __restrict__ hi, ushort* __restrict__ lo, int gid)
{
  int row = gid >> 7, kg = gid & 127;
  const float* p = in + ((size_t)row << 10) + (kg << 3);
  float4 a = FI4(p), b = FI4(p + 4);
  float v[8] = {a.x, a.y, a.z, a.w, b.x, b.y, b.z, b.w};
  u16x8 hv, lv;
  #pragma unroll
  for (int j = 0; j < 8; ++j) {
    unsigned short h = f2bf(v[j]);
    hv[j] = h;
    lv[j] = f2bf(v[j] - bf2f(h));
  }
  size_t o = swz_off(row, kg);
  *reinterpret_cast<u16x8*>(hi + o) = hv;
  *reinterpret_cast<u16x8*>(lo + o) = lv;
}

__device__ __forceinline__ void tsplit_body(
    const float* __restrict__ W, ushort* __restrict__ hi, ushort* __restrict__ lo, int gid)
{
  int n = gid & 1023, kg = gid >> 10;
  float v[8];
  #pragma unroll
  for (int j = 0; j < 8; ++j)
    v[j] = W[((size_t)(kg * 8 + j) << 10) + n];   // coalesced across lanes per j
  u16x8 hv, lv;
  #pragma unroll
  for (int j = 0; j < 8; ++j) {
    unsigned short h = f2bf(v[j]);
    hv[j] = h;
    lv[j] = f2bf(v[j] - bf2f(h));
  }
  size_t o = swz_off(n, kg);
  *reinterpret_cast<u16x8*>(hi + o) = hv;
  *reinterpret_cast<u16x8*>(lo + o) = lv;
}

__device__ __forceinline__ void build_r_body(
    ushort* __restrict__ hi, ushort* __restrict__ lo, int gid)
{
  int p = gid >> 7, kg = gid & 127;
  float pos = (float)(p - 1023);
  u16x8 hv, lv;
  #pragma unroll
  for (int j = 0; j < 8; ++j) {
    int c = kg * 8 + j;
    float ex = (float)(c & ~1) * (1.0f / 1024.0f);
    float invf = exp2f(-ex * 13.2877123795494f);   // 10000^-ex
    float ang = pos * invf;
    float val = (c & 1) ? cosf(ang) : sinf(ang);
    unsigned short h = f2bf(val);
    hv[j] = h;
    lv[j] = f2bf(val - bf2f(h));
  }
  size_t o = swz_off(p, kg);
  *reinterpret_cast<u16x8*>(hi + o) = hv;
  *reinterpret_cast<u16x8*>(lo + o) = lv;
}

// one launch: y = task {0:X-split 1:Y-split 2:Wo-split 3..6:W-transpose-splits 7:R-table}
__global__ __launch_bounds__(256) void pre_k(
    const float* X, const float* Y, const float* Wo,
    const float* Wq, const float* We, const float* Wv, const float* Wr,
    ushort* Xh, ushort* Xl, ushort* Yh, ushort* Yl, ushort* Woh, ushort* Wol,
    ushort* WqTh, ushort* WqTl, ushort* WeTh, ushort* WeTl,
    ushort* WvTh, ushort* WvTl, ushort* WrTh, ushort* WrTl,
    ushort* Rh, ushort* Rl)
{
  const int gid = blockIdx.x * 256 + threadIdx.x;
  switch (blockIdx.y) {
    case 0: split_body(X, Xh, Xl, gid); break;                       // 2048*128 = full grid
    case 1: split_body(Y, Yh, Yl, gid); break;
    case 2: if (gid < 1024*128) split_body(Wo, Woh, Wol, gid); break;
    case 3: if (gid < 1024*128) tsplit_body(Wq, WqTh, WqTl, gid); break;
    case 4: if (gid < 1024*128) tsplit_body(We, WeTh, WeTl, gid); break;
    case 5: if (gid < 1024*128) tsplit_body(Wv, WvTh, WvTl, gid); break;
    case 6: if (gid < 1024*128) tsplit_body(Wr, WrTh, WrTl, gid); break;
    default: if (gid < 2047*128) build_r_body(Rh, Rl, gid); break;
  }
}

// O-split after attention (separate: depends on attn output)
__global__ __launch_bounds__(256) void split_swz_k(
    const float* __restrict__ in, ushort* __restrict__ hi, ushort* __restrict__ lo, int rows)
{
  int gid = blockIdx.x * 256 + threadIdx.x;
  if (gid >= rows * 128) return;
  split_body(in, hi, lo, gid);
}

// ---------- split-bf16 MFMA GEMM core: C[M,1024] = A @ Bt^T ----------
template<int EPI>
__device__ __forceinline__ void gemm_core(
    ushort lds[4][4096],
    const ushort* __restrict__ Ah, const ushort* __restrict__ Al,
    const ushort* __restrict__ Bh, const ushort* __restrict__ Bl,
    float* __restrict__ C, int M,
    const float* __restrict__ bias, const float* __restrict__ resid)
{
  const int tid = threadIdx.x;
  const int w = tid >> 6, lane = tid & 63;
  const int tm = blockIdx.y, tn = blockIdx.x;
  const int wm = w >> 1, wn = w & 1;

  f32x4 acc[4][4];
  #pragma unroll
  for (int i = 0; i < 4; ++i)
    #pragma unroll
    for (int j = 0; j < 4; ++j)
      acc[i][j] = (f32x4){0.f, 0.f, 0.f, 0.f};

  const ushort* mysrc;
  if      (w == 0) mysrc = Ah + (((size_t)tm * 32) << 12);
  else if (w == 1) mysrc = Al + (((size_t)tm * 32) << 12);
  else if (w == 2) mysrc = Bh + (((size_t)tn * 32) << 12);
  else             mysrc = Bl + (((size_t)tn * 32) << 12);
  mysrc += lane * 8;
  ushort* mylds = &lds[w][0];

  for (int kt = 0; kt < 32; ++kt) {
    #pragma unroll
    for (int c = 0; c < 8; ++c)
      gload16(mysrc + c * 512, mylds + c * 512);   // 1KB per call per wave
    mysrc += 4096;
    __syncthreads();   // compiler drains vmcnt before s_barrier

    bf16x8 ah[4], al[4], bh4[4], bl4[4];
    #pragma unroll
    for (int i = 0; i < 4; ++i) {
      ah[i]  = *reinterpret_cast<const bf16x8*>(&lds[0][(wm*4 + i)*512 + lane*8]);
      al[i]  = *reinterpret_cast<const bf16x8*>(&lds[1][(wm*4 + i)*512 + lane*8]);
      bh4[i] = *reinterpret_cast<const bf16x8*>(&lds[2][(wn*4 + i)*512 + lane*8]);
      bl4[i] = *reinterpret_cast<const bf16x8*>(&lds[3][(wn*4 + i)*512 + lane*8]);
    }
    #pragma unroll
    for (int i = 0; i < 4; ++i)
      #pragma unroll
      for (int j = 0; j < 4; ++j) {
        acc[i][j] = __builtin_amdgcn_mfma_f32_16x16x32_bf16(ah[i], bh4[j], acc[i][j], 0, 0, 0);
        acc[i][j] = __builtin_amdgcn_mfma_f32_16x16x32_bf16(ah[i], bl4[j], acc[i][j], 0, 0, 0);
        acc[i][j] = __builtin_amdgcn_mfma_f32_16x16x32_bf16(al[i], bh4[j], acc[i][j], 0, 0, 0);
      }
    __syncthreads();
  }

  // C/D layout (verified m89/m91): col = lane&15, row = (lane>>4)*4 + reg
  const int r0 = tm*128 + wm*64 + ((lane >> 4) << 2);
  const int c0 = tn*128 + wn*64 + (lane & 15);
  #pragma unroll
  for (int i = 0; i < 4; ++i)
    #pragma unroll
    for (int r = 0; r < 4; ++r) {
      const int row = r0 + i*16 + r;
      if (row < M) {
        #pragma unroll
        for (int j = 0; j < 4; ++j) {
          const int col = c0 + j*16;
          float v = acc[i][j][r];
          if (EPI) v += bias[col] + resid[((size_t)row << 10) + col];
          C[((size_t)row << 10) + col] = v;
        }
      }
    }
}

// fused q/k/v/Qm projections: grid (8, 16, 4) -> 512 workgroups, full machine
__global__ __launch_bounds__(256, 2) void gemm4_k(
    const ushort* Xh, const ushort* Xl, const ushort* Yh, const ushort* Yl,
    const ushort* Rh, const ushort* Rl,
    const ushort* WqTh, const ushort* WqTl, const ushort* WeTh, const ushort* WeTl,
    const ushort* WvTh, const ushort* WvTl, const ushort* WrTh, const ushort* WrTl,
    float* qb, float* kb, float* vb, float* Qm)
{
  __shared__ ushort lds[4][4096];
  const int z = blockIdx.z;
  const ushort *Ah, *Al, *Bh, *Bl; float* C; int M = 2048;
  if (z == 0)      { Ah = Xh; Al = Xl; Bh = WqTh; Bl = WqTl; C = qb; }
  else if (z == 1) { Ah = Yh; Al = Yl; Bh = WeTh; Bl = WeTl; C = kb; }
  else if (z == 2) { Ah = Yh; Al = Yl; Bh = WvTh; Bl = WvTl; C = vb; }
  else             { Ah = Rh; Al = Rl; Bh = WrTh; Bl = WrTl; C = Qm; M = 2047; }
  gemm_core<0>(lds, Ah, Al, Bh, Bl, C, M, nullptr, nullptr);
}

// out-projection with bias + residual epilogue: Z = O @ Wo^T + b + X
__global__ __launch_bounds__(256, 2) void gemm_epi_k(
    const ushort* Oh, const ushort* Ol, const ushort* Wh, const ushort* Wl,
    float* Z, const float* bias, const float* resid)
{
  __shared__ ushort lds[4][4096];
  gemm_core<1>(lds, Oh, Ol, Wh, Wl, Z, 2048, bias, resid);
}

// ---------------- attention helpers ----------------
// slot -> (row within tile, k offset within 64) for fragment-order staging.
// slot s: sub = s>>6, fraglane = s&63; row = (sub>>1)*16 + (fl&15);
// k = (sub&1)*32 + ((fl>>4)<<3). Lane writes LDS at s*16B -> linear, conflict-free.
__device__ __forceinline__ void slot_rc(int s, int& row, int& ko) {
  int sub = s >> 6, fl = s & 63;
  row = (sub >> 1) * 16 + (fl & 15);
  ko  = ((sub & 1) << 5) + ((fl >> 4) << 3);
}
__device__ __forceinline__ void cvt8_store(ushort* __restrict__ hb, ushort* __restrict__ lb,
                                           int slot, float4 a, float4 b) {
  float v[8] = {a.x, a.y, a.z, a.w, b.x, b.y, b.z, b.w};
  u16x8 hv, lv;
  #pragma unroll
  for (int e = 0; e < 8; ++e) {
    unsigned short h = f2bf(v[e]);
    hv[e] = h;
    lv[e] = f2bf(v[e] - bf2f(h));
  }
  *reinterpret_cast<u16x8*>(hb + slot * 8) = hv;
  *reinterpret_cast<u16x8*>(lb + slot * 8) = lv;
}
__device__ __forceinline__ float4 add4(float4 a, float4 b) {
  return make_float4(a.x + b.x, a.y + b.y, a.z + b.z, a.w + b.w);
}

// ---------------- Fused causal attention, pipelined MFMA S-phase ----------------
// Per block: one (n, head, 32-query tile). Logit (j<=i):
//   (q_i+cb)·k_j + (1 + (i==j)) * (q_i+pb)·Qmat[j-i+1023]
// 2 barriers/tile; next tile's K/G prefetched to regs during MFMA, written to
// LDS after B1 (single-buffered frags are dead then). Sex/Srl rows are
// 16-lane-group private -> softmax/P-overlay/PV need no extra barriers.
__global__ __launch_bounds__(256, 2) void attn_k(
    const float* __restrict__ qg, const float* __restrict__ kg,
    const float* __restrict__ vg, const float* __restrict__ Qm,
    const float* __restrict__ cb, const float* __restrict__ pb,
    float* __restrict__ Og)
{
  __shared__ ushort Qch[2048], Qcl[2048], Qph[2048], Qpl[2048];  // q+cb, q+pb (32x64)
  __shared__ ushort Kh[4096], Kl[4096];                          // K tile (64x64)
  __shared__ ushort Gh[6144], Gl[6144];                          // Qm window (96x64)
  __shared__ float Sex[32][68];    // S exchange; later P exchange
  __shared__ float Srl[32][100];   // Srel exchange (cols 0..95)

  const int tid = threadIdx.x;
  const int tx = tid & 15, ty = tid >> 4;
  // XCD-bijective swizzle: nh = 8a+x pinned to XCD x; long diagonals first.
  const int p_ = blockIdx.x;
  const int x_ = p_ & 7, r_ = p_ >> 3;
  const int qt = 31 - (r_ & 31);
  const int nh = ((r_ >> 5) << 3) + x_;
  const int hh = nh & 15;
  const int n = nh >> 4;
  const int i0 = qt << 5;
  const int iA = ty << 1;               // 2 query rows per thread (softmax/PV phase)
  const size_t base = (size_t)n * (1024 * 1024) + (hh << 6);

  const int w = tid >> 6, lane = tid & 63;
  const int rb = w & 1;
  const int c0w = (w >> 1) * 5;
  const int rloc = (rb << 4) + ((lane >> 4) << 2);  // C row base (m89 layout)
  const int cloc = lane & 15;                        // C col

  // ---- prologue: stage Q (once) + K/G tile 0 ----
  {
    int row, ko;
    slot_rc(tid, row, ko);
    const float* qs = &qg[base + (size_t)(i0 + row) * 1024 + ko];
    float4 q0 = FI4(qs), q1 = FI4(qs + 4);
    float4 c0 = FI4(&cb[(hh << 6) + ko]), c1 = FI4(&cb[(hh << 6) + ko + 4]);
    float4 pp0 = FI4(&pb[(hh << 6) + ko]), pp1 = FI4(&pb[(hh << 6) + ko + 4]);
    float4 kp[2][2], gp[3][2];
    const int m00 = 992 - i0;
    #pragma unroll
    for (int i = 0; i < 2; ++i) {
      int rr, kk; slot_rc(tid + (i << 8), rr, kk);
      const float* src = &kg[base + (size_t)rr * 1024 + kk];
      kp[i][0] = FI4(src); kp[i][1] = FI4(src + 4);
    }
    #pragma unroll
    for (int i = 0; i < 3; ++i) {
      int rr, kk; slot_rc(tid + (i << 8), rr, kk);
      const float* src = &Qm[(size_t)(m00 + rr) * 1024 + (hh << 6) + kk];
      gp[i][0] = FI4(src); gp[i][1] = FI4(src + 4);
    }
    cvt8_store(Qch, Qcl, tid, add4(q0, c0), add4(q1, c1));
    cvt8_store(Qph, Qpl, tid, add4(q0, pp0), add4(q1, pp1));
    #pragma unroll
    for (int i = 0; i < 2; ++i) cvt8_store(Kh, Kl, tid + (i << 8), kp[i][0], kp[i][1]);
    #pragma unroll
    for (int i = 0; i < 3; ++i) cvt8_store(Gh, Gl, tid + (i << 8), gp[i][0], gp[i][1]);
  }
  __syncthreads();

  float m_run[2] = {-1e30f, -1e30f};
  float l_run[2] = {0.f, 0.f};
  float acc[2][4] = {{0.f,0.f,0.f,0.f},{0.f,0.f,0.f,0.f}};
  const int jt_max = (i0 + 31) >> 6;

  for (int jt = 0; jt <= jt_max; ++jt) {
    const int j0 = jt << 6;
    const bool pre = (jt < jt_max);

    // ---- issue next-tile K/G global reads (latency hides under MFMA) ----
    float4 kp[2][2], gp[3][2];
    if (pre) {
      const int j0n = j0 + 64, m0n = j0n - i0 + 992;
      #pragma unroll
      for (int i = 0; i < 2; ++i) {
        int rr, kk; slot_rc(tid + (i << 8), rr, kk);
        const float* src = &kg[base + (size_t)(j0n + rr) * 1024 + kk];
        kp[i][0] = FI4(src); kp[i][1] = FI4(src + 4);
      }
      #pragma unroll
      for (int i = 0; i < 3; ++i) {
        int rr, kk; slot_rc(tid + (i << 8), rr, kk);
        const float* src = &Qm[(size_t)(m0n + rr) * 1024 + (hh << 6) + kk];
        gp[i][0] = FI4(src); gp[i][1] = FI4(src + 4);
      }
    }

    // ---- MFMA: 5 C-subtiles per wave (3-pass split bf16, K=64 via 2 kblocks) ----
    f32x4 sacc[5];
    #pragma unroll
    for (int s = 0; s < 5; ++s) sacc[s] = (f32x4){0.f, 0.f, 0.f, 0.f};
    #pragma unroll
    for (int s = 0; s < 5; ++s) {
      const int c = c0w + s;
      const bool isK = (c < 4);
      const ushort* Ahp = isK ? Qch : Qph;
      const ushort* Alp = isK ? Qcl : Qpl;
      const ushort* Bhp = isK ? Kh : Gh;
      const ushort* Blp = isK ? Kl : Gl;
      const int cb_ = isK ? c : (c - 4);
      #pragma unroll
      for (int kb_ = 0; kb_ < 2; ++kb_) {
        const int aoff = ((((rb << 1) | kb_) << 9) + (lane << 3));
        const int boff = ((((cb_ << 1) | kb_) << 9) + (lane << 3));
        bf16x8 a_h = *reinterpret_cast<const bf16x8*>(Ahp + aoff);
        bf16x8 a_l = *reinterpret_cast<const bf16x8*>(Alp + aoff);
        bf16x8 b_h = *reinterpret_cast<const bf16x8*>(Bhp + boff);
        bf16x8 b_l = *reinterpret_cast<const bf16x8*>(Blp + boff);
        sacc[s] = __builtin_amdgcn_mfma_f32_16x16x32_bf16(a_h, b_h, sacc[s], 0, 0, 0);
        sacc[s] = __builtin_amdgcn_mfma_f32_16x16x32_bf16(a_h, b_l, sacc[s], 0, 0, 0);
        sacc[s] = __builtin_amdgcn_mfma_f32_16x16x32_bf16(a_l, b_h, sacc[s], 0, 0, 0);
      }
    }
    #pragma unroll
    for (int s = 0; s < 5; ++s) {
      const int c = c0w + s;
      #pragma unroll
      for (int reg = 0; reg < 4; ++reg) {
        if (c < 4) Sex[rloc + reg][(c << 4) + cloc] = sacc[s][reg];
        else       Srl[rloc + reg][((c - 4) << 4) + cloc] = sacc[s][reg];
      }
    }
    __syncthreads();   // B1: C-writes visible; K/G frag reads done

    // ---- softmax (rows are 16-lane-group private; wave-lockstep ordering) ----
    float p[2][4];
    #pragma unroll
    for (int di = 0; di < 2; ++di) {
      const int gi = i0 + iA + di;
      float mx = -1e30f;
      #pragma unroll
      for (int dj = 0; dj < 4; ++dj) {
        const int jl = tx + (dj << 4);
        const int gj = j0 + jl;
        float val = Sex[iA + di][jl]
                  + ((gj == gi) ? 2.0f : 1.0f) * Srl[iA + di][jl - iA - di + 31];
        val = (gj <= gi) ? val : -1e30f;
        p[di][dj] = val;
        mx = fmaxf(mx, val);
      }
      mx = fmaxf(mx, __shfl_xor(mx, 1));
      mx = fmaxf(mx, __shfl_xor(mx, 2));
      mx = fmaxf(mx, __shfl_xor(mx, 4));
      mx = fmaxf(mx, __shfl_xor(mx, 8));
      const float mnew = fmaxf(m_run[di], mx);
      const float sc = __expf(m_run[di] - mnew);
      float ps = 0.f;
      #pragma unroll
      for (int dj = 0; dj < 4; ++dj) {
        p[di][dj] = __expf(p[di][dj] - mnew);
        ps += p[di][dj];
      }
      ps += __shfl_xor(ps, 1);
      ps += __shfl_xor(ps, 2);
      ps += __shfl_xor(ps, 4);
      ps += __shfl_xor(ps, 8);
      l_run[di] = l_run[di] * sc + ps;
      m_run[di] = mnew;
      #pragma unroll
      for (int c2 = 0; c2 < 4; ++c2) acc[di][c2] *= sc;
    }
    #pragma unroll
    for (int di = 0; di < 2; ++di)
      #pragma unroll
      for (int dj = 0; dj < 4; ++dj)
        Sex[iA + di][tx + (dj << 4)] = p[di][dj];   // P overlays S (own rows, own wave)

    // ---- write next-tile K/G frags (LDS dead since B1) ----
    if (pre) {
      #pragma unroll
      for (int i = 0; i < 2; ++i) cvt8_store(Kh, Kl, tid + (i << 8), kp[i][0], kp[i][1]);
      #pragma unroll
      for (int i = 0; i < 3; ++i) cvt8_store(Gh, Gl, tid + (i << 8), gp[i][0], gp[i][1]);
    }

    // ---- PV (f32, V streamed via L1/L2) ----
    const float* vrow = vg + base + (size_t)j0 * 1024 + (tx << 2);
    #pragma unroll
    for (int jj = 0; jj < 64; jj += 4) {
      float4 p0 = FI4(&Sex[iA][jj]);
      float4 p1 = FI4(&Sex[iA + 1][jj]);
      float pp0[4] = {p0.x, p0.y, p0.z, p0.w};
      float pp1[4] = {p1.x, p1.y, p1.z, p1.w};
      #pragma unroll
      for (int u = 0; u < 4; ++u) {
        float4 vv = FI4(vrow + (size_t)(jj + u) * 1024);
        acc[0][0] += pp0[u] * vv.x; acc[0][1] += pp0[u] * vv.y;
        acc[0][2] += pp0[u] * vv.z; acc[0][3] += pp0[u] * vv.w;
        acc[1][0] += pp1[u] * vv.x; acc[1][1] += pp1[u] * vv.y;
        acc[1][2] += pp1[u] * vv.z; acc[1][3] += pp1[u] * vv.w;
      }
    }
    __syncthreads();   // B2: Sex reads done; K/G writes done
  }

  #pragma unroll
  for (int di = 0; di < 2; ++di) {
    const int gi = i0 + iA + di;
    const float inv = 1.0f / l_run[di];
    float4 o = make_float4(acc[di][0]*inv, acc[di][1]*inv,
                           acc[di][2]*inv, acc[di][3]*inv);
    FO4(&Og[base + (size_t)gi * 1024 + (tx << 2)]) = o;
  }
}

// ---------------- LayerNorm over rows of Z ----------------
__global__ __launch_bounds__(256) void ln_k(
    const float* __restrict__ Z, const float* __restrict__ g,
    const float* __restrict__ b, float* __restrict__ out)
{
  __shared__ float red[8];
  const int row = blockIdx.x;
  const int tid = threadIdx.x;
  const float* zr = Z + (size_t)row * 1024;
  float4 z = FI4(&zr[tid << 2]);
  float s = z.x + z.y + z.z + z.w;
  s += __shfl_xor(s, 32); s += __shfl_xor(s, 16); s += __shfl_xor(s, 8);
  s += __shfl_xor(s, 4);  s += __shfl_xor(s, 2);  s += __shfl_xor(s, 1);
  if ((tid & 63) == 0) red[tid >> 6] = s;
  __syncthreads();
  const float mu = (red[0] + red[1] + red[2] + red[3]) * (1.0f / 1024.0f);
  float4 d = make_float4(z.x - mu, z.y - mu, z.z - mu, z.w - mu);
  float sq = d.x*d.x + d.y*d.y + d.z*d.z + d.w*d.w;
  sq += __shfl_xor(sq, 32); sq += __shfl_xor(sq, 16); sq += __shfl_xor(sq, 8);
  sq += __shfl_xor(sq, 4);  sq += __shfl_xor(sq, 2);  sq += __shfl_xor(sq, 1);
  if ((tid & 63) == 0) red[4 + (tid >> 6)] = sq;
  __syncthreads();
  const float var = (red[4] + red[5] + red[6] + red[7]) * (1.0f / 1024.0f);
  const float inv = rsqrtf(var + 1e-5f);
  float4 gg = FI4(&g[tid << 2]);
  float4 bb = FI4(&b[tid << 2]);
  float4 o = make_float4(d.x*inv*gg.x + bb.x, d.y*inv*gg.y + bb.y,
                         d.z*inv*gg.z + bb.z, d.w*inv*gg.w + bb.w);
  FO4(&out[(size_t)row * 1024 + (tid << 2)]) = o;
}

extern "C" void kernel_launch(void* const* d_in, const int* in_sizes, int n_in,
                              void* d_out, int out_size, void* d_ws, size_t ws_size,
                              hipStream_t stream)
{
  const float* X   = (const float*)d_in[0];
  const float* Y   = (const float*)d_in[1];
  // d_in[2] = mask (causal), d_in[3] = h (16) — implied by structure
  const float* Wq  = (const float*)d_in[4];
  const float* We  = (const float*)d_in[5];
  const float* Wv  = (const float*)d_in[6];
  const float* Wr  = (const float*)d_in[7];
  const float* cb  = (const float*)d_in[8];
  const float* pb  = (const float*)d_in[9];
  const float* Wo  = (const float*)d_in[10];
  const float* Wob = (const float*)d_in[11];
  const float* lng = (const float*)d_in[12];
  const float* lnb = (const float*)d_in[13];
  float* out = (float*)d_out;
  char* base = (char*)d_ws;

  const size_t MB = 1u << 20;
  // 76 MB total, with sequential-lifetime aliasing
  float*  qb   = (float*)(base + 0*MB);
  float*  kb   = (float*)(base + 8*MB);
  float*  vb   = (float*)(base + 16*MB);
  float*  Qm   = (float*)(base + 24*MB);
  ushort* Xh   = (ushort*)(base + 32*MB);   // -> later Oh
  ushort* Xl   = (ushort*)(base + 36*MB);   // -> later Ol
  ushort* Yh   = (ushort*)(base + 40*MB);   // -> later Zb (f32, 8MB)
  ushort* Yl   = (ushort*)(base + 44*MB);
  ushort* Rh   = (ushort*)(base + 48*MB);   // -> later Ob (f32, 8MB)
  ushort* Rl   = (ushort*)(base + 52*MB);
  ushort* Oh   = Xh;
  ushort* Ol   = Xl;
  float*  Zb   = (float*)(base + 40*MB);
  float*  Ob   = (float*)(base + 48*MB);
  ushort* WqTh = (ushort*)(base + 56*MB);
  ushort* WqTl = (ushort*)(base + 58*MB);
  ushort* WeTh = (ushort*)(base + 60*MB);
  ushort* WeTl = (ushort*)(base + 62*MB);
  ushort* WvTh = (ushort*)(base + 64*MB);
  ushort* WvTl = (ushort*)(base + 66*MB);
  ushort* WrTh = (ushort*)(base + 68*MB);
  ushort* WrTl = (ushort*)(base + 70*MB);
  ushort* Woh  = (ushort*)(base + 72*MB);
  ushort* Wol  = (ushort*)(base + 74*MB);

  // ---- all preprocessing in ONE launch (splits / transposes / R table) ----
  pre_k<<<dim3(1024, 8), dim3(256), 0, stream>>>(
      X, Y, Wo, Wq, We, Wv, Wr,
      Xh, Xl, Yh, Yl, Woh, Wol,
      WqTh, WqTl, WeTh, WeTl, WvTh, WvTl, WrTh, WrTl,
      Rh, Rl);

  // ---- fused q/k/v/Qm projections on MFMA ----
  gemm4_k<<<dim3(8, 16, 4), dim3(256), 0, stream>>>(
      Xh, Xl, Yh, Yl, Rh, Rl,
      WqTh, WqTl, WeTh, WeTl, WvTh, WvTl, WrTh, WrTl,
      qb, kb, vb, Qm);

  // ---- fused attention (pipelined MFMA S-phase + f32 softmax/PV) ----
  attn_k<<<dim3(1024), dim3(256), 0, stream>>>(qb, kb, vb, Qm, cb, pb, Ob);

  // ---- out-projection on MFMA (+bias +residual), then LayerNorm ----
  split_swz_k<<<dim3(1024), dim3(256), 0, stream>>>(Ob, Oh, Ol, 2048);
  gemm_epi_k<<<dim3(8, 16), dim3(256), 0, stream>>>(Oh, Ol, Woh, Wol, Zb, Wob, X);
  ln_k<<<dim3(2048), dim3(256), 0, stream>>>(Zb, lng, lnb, out);
}

// Round 6
// 289.290 us; speedup vs baseline: 1.9711x; 1.3672x over previous
//
#include <hip/hip_runtime.h>
#include <math.h>

typedef __attribute__((ext_vector_type(4))) float f32x4;
typedef __attribute__((ext_vector_type(8))) short bf16x8;       // 8 bf16 in 4 VGPRs
typedef __attribute__((ext_vector_type(8))) unsigned short u16x8;

#define FI4(p) (*reinterpret_cast<const float4*>(p))
#define FO4(p) (*reinterpret_cast<float4*>(p))

// ---------- bf16 split helpers (round-to-nearest-even) ----------
__device__ __forceinline__ unsigned short f2bf(float x) {
  unsigned u = __float_as_uint(x);
  u += 0x7FFFu + ((u >> 16) & 1u);
  return (unsigned short)(u >> 16);
}
__device__ __forceinline__ float bf2f(unsigned short h) {
  return __uint_as_float(((unsigned)h) << 16);
}

// Fragment-order swizzled offset for logical row-major [rows][1024] matrices.
// Tile = 128 rows x 32 k, stored [tm][kt][s][lane][8]:
//   s = sub-tile of 16 rows, lane = ((k>>3)&3)*16 + (row&15), j = k&7.
__device__ __forceinline__ size_t swz_off(int row, int kg) {   // kg = k/8
  int tm = row >> 7;
  int kt = kg >> 2;
  int s  = (row & 127) >> 4;
  int lane = ((kg & 3) << 4) | (row & 15);
  return (((size_t)(tm * 32 + kt)) << 12) + ((size_t)s << 9) + ((size_t)lane << 3);
}

__device__ __forceinline__ void gload16(const ushort* g, ushort* l) {
  __builtin_amdgcn_global_load_lds((const __attribute__((address_space(1))) void*)(g),
                                   (__attribute__((address_space(3))) void*)(l), 16, 0, 0);
}

// ---------- preprocessing task bodies ----------
__device__ __forceinline__ void split_body(
    const float* __restrict__ in, ushort* __restrict__ hi, ushort* __restrict__ lo, int gid)
{
  int row = gid >> 7, kg = gid & 127;
  const float* p = in + ((size_t)row << 10) + (kg << 3);
  float4 a = FI4(p), b = FI4(p + 4);
  float v[8] = {a.x, a.y, a.z, a.w, b.x, b.y, b.z, b.w};
  u16x8 hv, lv;
  #pragma unroll
  for (int j = 0; j < 8; ++j) {
    unsigned short h = f2bf(v[j]);
    hv[j] = h;
    lv[j] = f2bf(v[j] - bf2f(h));
  }
  size_t o = swz_off(row, kg);
  *reinterpret_cast<u16x8*>(hi + o) = hv;
  *reinterpret_cast<u16x8*>(lo + o) = lv;
}

__device__ __forceinline__ void tsplit_body(
    const float* __restrict__ W, ushort* __restrict__ hi, ushort* __restrict__ lo, int gid)
{
  int n = gid & 1023, kg = gid >> 10;
  float v[8];
  #pragma unroll
  for (int j = 0; j < 8; ++j)
    v[j] = W[((size_t)(kg * 8 + j) << 10) + n];   // coalesced across lanes per j
  u16x8 hv, lv;
  #pragma unroll
  for (int j = 0; j < 8; ++j) {
    unsigned short h = f2bf(v[j]);
    hv[j] = h;
    lv[j] = f2bf(v[j] - bf2f(h));
  }
  size_t o = swz_off(n, kg);
  *reinterpret_cast<u16x8*>(hi + o) = hv;
  *reinterpret_cast<u16x8*>(lo + o) = lv;
}

__device__ __forceinline__ void build_r_body(
    ushort* __restrict__ hi, ushort* __restrict__ lo, int gid)
{
  int p = gid >> 7, kg = gid & 127;
  float pos = (float)(p - 1023);
  u16x8 hv, lv;
  #pragma unroll
  for (int j = 0; j < 8; ++j) {
    int c = kg * 8 + j;
    float ex = (float)(c & ~1) * (1.0f / 1024.0f);
    float invf = exp2f(-ex * 13.2877123795494f);   // 10000^-ex
    float ang = pos * invf;
    float val = (c & 1) ? cosf(ang) : sinf(ang);
    unsigned short h = f2bf(val);
    hv[j] = h;
    lv[j] = f2bf(val - bf2f(h));
  }
  size_t o = swz_off(p, kg);
  *reinterpret_cast<u16x8*>(hi + o) = hv;
  *reinterpret_cast<u16x8*>(lo + o) = lv;
}

// one launch: y = task {0:X-split 1:Y-split 2:Wo-split 3..6:W-transpose-splits 7:R-table}
__global__ __launch_bounds__(256) void pre_k(
    const float* X, const float* Y, const float* Wo,
    const float* Wq, const float* We, const float* Wv, const float* Wr,
    ushort* Xh, ushort* Xl, ushort* Yh, ushort* Yl, ushort* Woh, ushort* Wol,
    ushort* WqTh, ushort* WqTl, ushort* WeTh, ushort* WeTl,
    ushort* WvTh, ushort* WvTl, ushort* WrTh, ushort* WrTl,
    ushort* Rh, ushort* Rl)
{
  const int gid = blockIdx.x * 256 + threadIdx.x;
  switch (blockIdx.y) {
    case 0: split_body(X, Xh, Xl, gid); break;                       // 2048*128 = full grid
    case 1: split_body(Y, Yh, Yl, gid); break;
    case 2: if (gid < 1024*128) split_body(Wo, Woh, Wol, gid); break;
    case 3: if (gid < 1024*128) tsplit_body(Wq, WqTh, WqTl, gid); break;
    case 4: if (gid < 1024*128) tsplit_body(We, WeTh, WeTl, gid); break;
    case 5: if (gid < 1024*128) tsplit_body(Wv, WvTh, WvTl, gid); break;
    case 6: if (gid < 1024*128) tsplit_body(Wr, WrTh, WrTl, gid); break;
    default: if (gid < 2047*128) build_r_body(Rh, Rl, gid); break;
  }
}

// O-split after attention (separate: depends on attn output)
__global__ __launch_bounds__(256) void split_swz_k(
    const float* __restrict__ in, ushort* __restrict__ hi, ushort* __restrict__ lo, int rows)
{
  int gid = blockIdx.x * 256 + threadIdx.x;
  if (gid >= rows * 128) return;
  split_body(in, hi, lo, gid);
}

// ---------- split-bf16 MFMA GEMM core: C[M,1024] = A @ Bt^T ----------
template<int EPI>
__device__ __forceinline__ void gemm_core(
    ushort lds[4][4096],
    const ushort* __restrict__ Ah, const ushort* __restrict__ Al,
    const ushort* __restrict__ Bh, const ushort* __restrict__ Bl,
    float* __restrict__ C, int M,
    const float* __restrict__ bias, const float* __restrict__ resid)
{
  const int tid = threadIdx.x;
  const int w = tid >> 6, lane = tid & 63;
  const int tm = blockIdx.y, tn = blockIdx.x;
  const int wm = w >> 1, wn = w & 1;

  f32x4 acc[4][4];
  #pragma unroll
  for (int i = 0; i < 4; ++i)
    #pragma unroll
    for (int j = 0; j < 4; ++j)
      acc[i][j] = (f32x4){0.f, 0.f, 0.f, 0.f};

  const ushort* mysrc;
  if      (w == 0) mysrc = Ah + (((size_t)tm * 32) << 12);
  else if (w == 1) mysrc = Al + (((size_t)tm * 32) << 12);
  else if (w == 2) mysrc = Bh + (((size_t)tn * 32) << 12);
  else             mysrc = Bl + (((size_t)tn * 32) << 12);
  mysrc += lane * 8;
  ushort* mylds = &lds[w][0];

  for (int kt = 0; kt < 32; ++kt) {
    #pragma unroll
    for (int c = 0; c < 8; ++c)
      gload16(mysrc + c * 512, mylds + c * 512);   // 1KB per call per wave
    mysrc += 4096;
    __syncthreads();   // compiler drains vmcnt before s_barrier

    bf16x8 ah[4], al[4], bh4[4], bl4[4];
    #pragma unroll
    for (int i = 0; i < 4; ++i) {
      ah[i]  = *reinterpret_cast<const bf16x8*>(&lds[0][(wm*4 + i)*512 + lane*8]);
      al[i]  = *reinterpret_cast<const bf16x8*>(&lds[1][(wm*4 + i)*512 + lane*8]);
      bh4[i] = *reinterpret_cast<const bf16x8*>(&lds[2][(wn*4 + i)*512 + lane*8]);
      bl4[i] = *reinterpret_cast<const bf16x8*>(&lds[3][(wn*4 + i)*512 + lane*8]);
    }
    #pragma unroll
    for (int i = 0; i < 4; ++i)
      #pragma unroll
      for (int j = 0; j < 4; ++j) {
        acc[i][j] = __builtin_amdgcn_mfma_f32_16x16x32_bf16(ah[i], bh4[j], acc[i][j], 0, 0, 0);
        acc[i][j] = __builtin_amdgcn_mfma_f32_16x16x32_bf16(ah[i], bl4[j], acc[i][j], 0, 0, 0);
        acc[i][j] = __builtin_amdgcn_mfma_f32_16x16x32_bf16(al[i], bh4[j], acc[i][j], 0, 0, 0);
      }
    __syncthreads();
  }

  // C/D layout (verified m89/m91): col = lane&15, row = (lane>>4)*4 + reg
  const int r0 = tm*128 + wm*64 + ((lane >> 4) << 2);
  const int c0 = tn*128 + wn*64 + (lane & 15);
  #pragma unroll
  for (int i = 0; i < 4; ++i)
    #pragma unroll
    for (int r = 0; r < 4; ++r) {
      const int row = r0 + i*16 + r;
      if (row < M) {
        #pragma unroll
        for (int j = 0; j < 4; ++j) {
          const int col = c0 + j*16;
          float v = acc[i][j][r];
          if (EPI) v += bias[col] + resid[((size_t)row << 10) + col];
          C[((size_t)row << 10) + col] = v;
        }
      }
    }
}

// fused q/k/v/Qm projections: grid (8, 16, 4) -> 512 workgroups, full machine
__global__ __launch_bounds__(256, 2) void gemm4_k(
    const ushort* Xh, const ushort* Xl, const ushort* Yh, const ushort* Yl,
    const ushort* Rh, const ushort* Rl,
    const ushort* WqTh, const ushort* WqTl, const ushort* WeTh, const ushort* WeTl,
    const ushort* WvTh, const ushort* WvTl, const ushort* WrTh, const ushort* WrTl,
    float* qb, float* kb, float* vb, float* Qm)
{
  __shared__ ushort lds[4][4096];
  const int z = blockIdx.z;
  const ushort *Ah, *Al, *Bh, *Bl; float* C; int M = 2048;
  if (z == 0)      { Ah = Xh; Al = Xl; Bh = WqTh; Bl = WqTl; C = qb; }
  else if (z == 1) { Ah = Yh; Al = Yl; Bh = WeTh; Bl = WeTl; C = kb; }
  else if (z == 2) { Ah = Yh; Al = Yl; Bh = WvTh; Bl = WvTl; C = vb; }
  else             { Ah = Rh; Al = Rl; Bh = WrTh; Bl = WrTl; C = Qm; M = 2047; }
  gemm_core<0>(lds, Ah, Al, Bh, Bl, C, M, nullptr, nullptr);
}

// out-projection with bias + residual epilogue: Z = O @ Wo^T + b + X
__global__ __launch_bounds__(256, 2) void gemm_epi_k(
    const ushort* Oh, const ushort* Ol, const ushort* Wh, const ushort* Wl,
    float* Z, const float* bias, const float* resid)
{
  __shared__ ushort lds[4][4096];
  gemm_core<1>(lds, Oh, Ol, Wh, Wl, Z, 2048, bias, resid);
}

// ---------------- attention helpers ----------------
// slot -> (row within tile, k offset within 64) for fragment-order staging.
__device__ __forceinline__ void slot_rc(int s, int& row, int& ko) {
  int sub = s >> 6, fl = s & 63;
  row = (sub >> 1) * 16 + (fl & 15);
  ko  = ((sub & 1) << 5) + ((fl >> 4) << 3);
}
__device__ __forceinline__ void cvt8_store(ushort* __restrict__ hb, ushort* __restrict__ lb,
                                           int slot, float4 a, float4 b) {
  float v[8] = {a.x, a.y, a.z, a.w, b.x, b.y, b.z, b.w};
  u16x8 hv, lv;
  #pragma unroll
  for (int e = 0; e < 8; ++e) {
    unsigned short h = f2bf(v[e]);
    hv[e] = h;
    lv[e] = f2bf(v[e] - bf2f(h));
  }
  *reinterpret_cast<u16x8*>(hb + slot * 8) = hv;
  *reinterpret_cast<u16x8*>(lb + slot * 8) = lv;
}

// ---------------- Fused causal attention: role-split MFMA flash ----------------
// Per block: one (n, head, 32-query tile). Logit (j<=i):
//   (q_i+cb)·k_j + (1 + (i==j)) * (q_i+pb)·Qmat[j-i+1023]
// Waves 0,1 = S-waves (QK^T 4 subtiles, in-reg softmax for rows rb*16..+15).
// Waves 2,3 = R-waves (Srel 6 subtiles -> Srl; stage V(cur)+K/G(next) in phase B).
// All waves: PV on MFMA (P via XOR-swizzled bf16 strip). 3 barriers/tile.
__global__ __launch_bounds__(256, 2) void attn_k(
    const float* __restrict__ qg, const float* __restrict__ kg,
    const float* __restrict__ vg, const float* __restrict__ Qm,
    const float* __restrict__ cbv, const float* __restrict__ pbv,
    float* __restrict__ Og)
{
  __shared__ ushort Kh[4096], Kl[4096];   // K tile 64x64, frag order
  __shared__ ushort Gh[6144], Gl[6144];   // Qm window 96x64, frag order
  __shared__ ushort Vh[4096];             // V tile (B-frag: col=feat, k=key), hi only
  __shared__ ushort Ph[2048];             // P strips [rb][row16][key64], XOR-swizzled
  __shared__ float  Srl[32][100];         // Srel exchange (cols 0..95)
  __shared__ float  scL[64];              // [0..31] per-tile sc, [32..63] final 1/l

  const int tid = threadIdx.x;
  const int w = tid >> 6, lane = tid & 63;
  const int g = lane >> 4, c0 = lane & 15;
  // dispatch: globally heaviest-first; nh -> XCD pinned (nh&7 == blockIdx&7)
  const int p_ = blockIdx.x;
  const int qt = 31 - (p_ >> 5);
  const int nh = p_ & 31;
  const int hh = nh & 15;
  const int n = nh >> 4;
  const int i0 = qt << 5;
  const size_t base = (size_t)n * (1024 * 1024) + (hh << 6);

  const bool isS = (w < 2);
  const int rb = isS ? w : (w - 2);       // rowblock for phase A/B role
  const int rb_pv = w & 1;                // rowblock for PV/output
  const int cbb = (w >> 1) << 1;          // feat colblock base for PV/output

  // ---- Q fragments in registers (A-frag: row=lane&15, k=(lane>>4)*8+j) ----
  bf16x8 qa_h[2], qa_l[2];
  {
    const float* qbias = isS ? cbv : pbv;
    const int qrow = i0 + rb * 16 + c0;
    #pragma unroll
    for (int kb = 0; kb < 2; ++kb) {
      u16x8 hv, lv;
      #pragma unroll
      for (int j = 0; j < 8; ++j) {
        const int k = kb * 32 + g * 8 + j;
        float v = qg[base + ((size_t)qrow << 10) + k] + qbias[(hh << 6) + k];
        unsigned short h = f2bf(v);
        hv[j] = h;
        lv[j] = f2bf(v - bf2f(h));
      }
      qa_h[kb] = *reinterpret_cast<bf16x8*>(&hv);
      qa_l[kb] = *reinterpret_cast<bf16x8*>(&lv);
    }
  }

  // ---- prologue: stage K_0 (512 slots) and G_0 (768 slots) with all 256 threads ----
  {
    const int m00 = 992 - i0;
    #pragma unroll
    for (int i = 0; i < 2; ++i) {
      int row, ko; slot_rc(tid + (i << 8), row, ko);
      const float* src = &kg[base + ((size_t)row << 10) + ko];
      cvt8_store(Kh, Kl, tid + (i << 8), FI4(src), FI4(src + 4));
    }
    #pragma unroll
    for (int i = 0; i < 3; ++i) {
      int row, ko; slot_rc(tid + (i << 8), row, ko);
      const float* src = &Qm[((size_t)(m00 + row) << 10) + (hh << 6) + ko];
      cvt8_store(Gh, Gl, tid + (i << 8), FI4(src), FI4(src + 4));
    }
  }
  __syncthreads();

  f32x4 acc_o[2];
  acc_o[0] = (f32x4){0.f, 0.f, 0.f, 0.f};
  acc_o[1] = (f32x4){0.f, 0.f, 0.f, 0.f};
  float m_[4] = {-1e30f, -1e30f, -1e30f, -1e30f};
  float l_[4] = {0.f, 0.f, 0.f, 0.f};
  float sc_[4] = {0.f, 0.f, 0.f, 0.f};
  const int jt_max = (i0 + 31) >> 6;

  for (int jt = 0; jt <= jt_max; ++jt) {
    const int j0 = jt << 6;
    const bool pre = (jt < jt_max);
    const int m0 = j0 - i0 + 992;

    // ================= phase A: S/Srel MFMA =================
    f32x4 sa[6];
    #pragma unroll
    for (int s = 0; s < 6; ++s) sa[s] = (f32x4){0.f, 0.f, 0.f, 0.f};
    if (isS) {
      #pragma unroll
      for (int cb2 = 0; cb2 < 4; ++cb2) {
        #pragma unroll
        for (int kb = 0; kb < 2; ++kb) {
          const int off = (((cb2 << 1) | kb) << 9) + (lane << 3);
          const bf16x8 bh = *reinterpret_cast<const bf16x8*>(Kh + off);
          const bf16x8 bl = *reinterpret_cast<const bf16x8*>(Kl + off);
          sa[cb2] = __builtin_amdgcn_mfma_f32_16x16x32_bf16(qa_h[kb], bh, sa[cb2], 0, 0, 0);
          sa[cb2] = __builtin_amdgcn_mfma_f32_16x16x32_bf16(qa_h[kb], bl, sa[cb2], 0, 0, 0);
          sa[cb2] = __builtin_amdgcn_mfma_f32_16x16x32_bf16(qa_l[kb], bh, sa[cb2], 0, 0, 0);
        }
      }
    } else {
      #pragma unroll
      for (int cb2 = 0; cb2 < 6; ++cb2) {
        #pragma unroll
        for (int kb = 0; kb < 2; ++kb) {
          const int off = (((cb2 << 1) | kb) << 9) + (lane << 3);
          const bf16x8 bh = *reinterpret_cast<const bf16x8*>(Gh + off);
          const bf16x8 bl = *reinterpret_cast<const bf16x8*>(Gl + off);
          sa[cb2] = __builtin_amdgcn_mfma_f32_16x16x32_bf16(qa_h[kb], bh, sa[cb2], 0, 0, 0);
          sa[cb2] = __builtin_amdgcn_mfma_f32_16x16x32_bf16(qa_h[kb], bl, sa[cb2], 0, 0, 0);
          sa[cb2] = __builtin_amdgcn_mfma_f32_16x16x32_bf16(qa_l[kb], bh, sa[cb2], 0, 0, 0);
        }
      }
      // write Srel C-frags (row=(lane>>4)*4+reg, col=lane&15)
      #pragma unroll
      for (int cb2 = 0; cb2 < 6; ++cb2)
        #pragma unroll
        for (int reg = 0; reg < 4; ++reg)
          Srl[rb * 16 + g * 4 + reg][cb2 * 16 + c0] = sa[cb2][reg];
    }
    __syncthreads();   // B1: Srl visible; K/G frag reads done

    // ================= phase B: softmax (S) | staging (R) =================
    if (isS) {
      #pragma unroll
      for (int reg = 0; reg < 4; ++reg) {
        const int row = rb * 16 + g * 4 + reg;   // 0..31
        const int d_ = row + i0 - j0;
        float vals[4];
        float mx = -1e30f;
        #pragma unroll
        for (int c = 0; c < 4; ++c) {
          const int jl = (c << 4) + c0;
          const float rel = Srl[row][jl + 31 - row];
          float v = sa[c][reg] + ((jl == d_) ? 2.0f : 1.0f) * rel;
          v = (jl <= d_) ? v : -1e30f;
          vals[c] = v;
          mx = fmaxf(mx, v);
        }
        mx = fmaxf(mx, __shfl_xor(mx, 1));
        mx = fmaxf(mx, __shfl_xor(mx, 2));
        mx = fmaxf(mx, __shfl_xor(mx, 4));
        mx = fmaxf(mx, __shfl_xor(mx, 8));
        const float mnew = fmaxf(m_[reg], mx);
        sc_[reg] = __expf(m_[reg] - mnew);
        float ps = 0.f;
        float pv_[4];
        #pragma unroll
        for (int c = 0; c < 4; ++c) {
          pv_[c] = __expf(vals[c] - mnew);
          ps += pv_[c];
        }
        ps += __shfl_xor(ps, 1);
        ps += __shfl_xor(ps, 2);
        ps += __shfl_xor(ps, 4);
        ps += __shfl_xor(ps, 8);
        l_[reg] = l_[reg] * sc_[reg] + ps;
        m_[reg] = mnew;
        // write P strip (bf16, XOR swizzle on strip-local row)
        const int rl = g * 4 + reg;
        #pragma unroll
        for (int c = 0; c < 4; ++c) {
          int ua = (rb << 10) + (rl << 6) + (c << 4) + c0;
          ua ^= (rl & 7) << 3;
          Ph[ua] = f2bf(pv_[c]);
        }
        if (c0 == 0) scL[row] = sc_[reg];
      }
    } else {
      const int rt = tid & 127;
      // stage V (current tile): transposed gather, hi only
      #pragma unroll
      for (int i = 0; i < 4; ++i) {
        const int s = rt + (i << 7);
        const int sub = s >> 6, fl = s & 63;
        const int feat = ((sub >> 1) << 4) + (fl & 15);
        const int key0 = ((sub & 1) << 5) + ((fl >> 4) << 3);
        const float* src = &vg[base + ((size_t)(j0 + key0) << 10) + feat];
        u16x8 hv;
        #pragma unroll
        for (int j = 0; j < 8; ++j) hv[j] = f2bf(src[(size_t)j << 10]);
        *reinterpret_cast<u16x8*>(Vh + s * 8) = hv;
      }
      if (pre) {
        #pragma unroll
        for (int i = 0; i < 4; ++i) {
          const int s = rt + (i << 7);
          int row, ko; slot_rc(s, row, ko);
          const float* src = &kg[base + ((size_t)(j0 + 64 + row) << 10) + ko];
          cvt8_store(Kh, Kl, s, FI4(src), FI4(src + 4));
        }
        #pragma unroll
        for (int i = 0; i < 6; ++i) {
          const int s = rt + (i << 7);
          int row, ko; slot_rc(s, row, ko);
          const float* src = &Qm[((size_t)(m0 + 64 + row) << 10) + (hh << 6) + ko];
          cvt8_store(Gh, Gl, s, FI4(src), FI4(src + 4));
        }
      }
    }
    __syncthreads();   // B2: P/V/scL ready

    // ================= phase C: PV MFMA =================
    {
      float scc[4];
      if (isS) {
        #pragma unroll
        for (int reg = 0; reg < 4; ++reg) scc[reg] = sc_[reg];
      } else {
        #pragma unroll
        for (int reg = 0; reg < 4; ++reg) scc[reg] = scL[(rb_pv << 4) + g * 4 + reg];
      }
      bf16x8 pa[2];
      #pragma unroll
      for (int kkb = 0; kkb < 2; ++kkb) {
        int ua = (rb_pv << 10) + (c0 << 6) + (kkb << 5) + (g << 3);
        ua ^= (c0 & 7) << 3;
        pa[kkb] = *reinterpret_cast<const bf16x8*>(Ph + ua);
      }
      #pragma unroll
      for (int cbi = 0; cbi < 2; ++cbi) {
        #pragma unroll
        for (int reg = 0; reg < 4; ++reg) acc_o[cbi][reg] *= scc[reg];
        #pragma unroll
        for (int kkb = 0; kkb < 2; ++kkb) {
          const bf16x8 vb = *reinterpret_cast<const bf16x8*>(
              Vh + ((((cbb + cbi) << 1) | kkb) << 9) + (lane << 3));
          acc_o[cbi] = __builtin_amdgcn_mfma_f32_16x16x32_bf16(pa[kkb], vb, acc_o[cbi], 0, 0, 0);
        }
      }
    }
    __syncthreads();   // B3: PV reads done; next staging may overwrite
  }

  // ---- epilogue: exchange 1/l, scale, store ----
  if (isS && c0 == 0) {
    #pragma unroll
    for (int reg = 0; reg < 4; ++reg)
      scL[32 + rb * 16 + g * 4 + reg] = 1.0f / l_[reg];
  }
  __syncthreads();
  float inv[4];
  if (isS) {
    #pragma unroll
    for (int reg = 0; reg < 4; ++reg) inv[reg] = 1.0f / l_[reg];
  } else {
    #pragma unroll
    for (int reg = 0; reg < 4; ++reg) inv[reg] = scL[32 + (rb_pv << 4) + g * 4 + reg];
  }
  #pragma unroll
  for (int cbi = 0; cbi < 2; ++cbi)
    #pragma unroll
    for (int reg = 0; reg < 4; ++reg)
      Og[base + ((size_t)(i0 + rb_pv * 16 + g * 4 + reg) << 10) + ((cbb + cbi) << 4) + c0] =
          acc_o[cbi][reg] * inv[reg];
}

// ---------------- LayerNorm over rows of Z ----------------
__global__ __launch_bounds__(256) void ln_k(
    const float* __restrict__ Z, const float* __restrict__ g,
    const float* __restrict__ b, float* __restrict__ out)
{
  __shared__ float red[8];
  const int row = blockIdx.x;
  const int tid = threadIdx.x;
  const float* zr = Z + (size_t)row * 1024;
  float4 z = FI4(&zr[tid << 2]);
  float s = z.x + z.y + z.z + z.w;
  s += __shfl_xor(s, 32); s += __shfl_xor(s, 16); s += __shfl_xor(s, 8);
  s += __shfl_xor(s, 4);  s += __shfl_xor(s, 2);  s += __shfl_xor(s, 1);
  if ((tid & 63) == 0) red[tid >> 6] = s;
  __syncthreads();
  const float mu = (red[0] + red[1] + red[2] + red[3]) * (1.0f / 1024.0f);
  float4 d = make_float4(z.x - mu, z.y - mu, z.z - mu, z.w - mu);
  float sq = d.x*d.x + d.y*d.y + d.z*d.z + d.w*d.w;
  sq += __shfl_xor(sq, 32); sq += __shfl_xor(sq, 16); sq += __shfl_xor(sq, 8);
  sq += __shfl_xor(sq, 4);  sq += __shfl_xor(sq, 2);  sq += __shfl_xor(sq, 1);
  if ((tid & 63) == 0) red[4 + (tid >> 6)] = sq;
  __syncthreads();
  const float var = (red[4] + red[5] + red[6] + red[7]) * (1.0f / 1024.0f);
  const float inv = rsqrtf(var + 1e-5f);
  float4 gg = FI4(&g[tid << 2]);
  float4 bb = FI4(&b[tid << 2]);
  float4 o = make_float4(d.x*inv*gg.x + bb.x, d.y*inv*gg.y + bb.y,
                         d.z*inv*gg.z + bb.z, d.w*inv*gg.w + bb.w);
  FO4(&out[(size_t)row * 1024 + (tid << 2)]) = o;
}

extern "C" void kernel_launch(void* const* d_in, const int* in_sizes, int n_in,
                              void* d_out, int out_size, void* d_ws, size_t ws_size,
                              hipStream_t stream)
{
  const float* X   = (const float*)d_in[0];
  const float* Y   = (const float*)d_in[1];
  // d_in[2] = mask (causal), d_in[3] = h (16) — implied by structure
  const float* Wq  = (const float*)d_in[4];
  const float* We  = (const float*)d_in[5];
  const float* Wv  = (const float*)d_in[6];
  const float* Wr  = (const float*)d_in[7];
  const float* cb  = (const float*)d_in[8];
  const float* pb  = (const float*)d_in[9];
  const float* Wo  = (const float*)d_in[10];
  const float* Wob = (const float*)d_in[11];
  const float* lng = (const float*)d_in[12];
  const float* lnb = (const float*)d_in[13];
  float* out = (float*)d_out;
  char* base = (char*)d_ws;

  const size_t MB = 1u << 20;
  // 76 MB total, with sequential-lifetime aliasing
  float*  qb   = (float*)(base + 0*MB);
  float*  kb   = (float*)(base + 8*MB);
  float*  vb   = (float*)(base + 16*MB);
  float*  Qm   = (float*)(base + 24*MB);
  ushort* Xh   = (ushort*)(base + 32*MB);   // -> later Oh
  ushort* Xl   = (ushort*)(base + 36*MB);   // -> later Ol
  ushort* Yh   = (ushort*)(base + 40*MB);   // -> later Zb (f32, 8MB)
  ushort* Yl   = (ushort*)(base + 44*MB);
  ushort* Rh   = (ushort*)(base + 48*MB);   // -> later Ob (f32, 8MB)
  ushort* Rl   = (ushort*)(base + 52*MB);
  ushort* Oh   = Xh;
  ushort* Ol   = Xl;
  float*  Zb   = (float*)(base + 40*MB);
  float*  Ob   = (float*)(base + 48*MB);
  ushort* WqTh = (ushort*)(base + 56*MB);
  ushort* WqTl = (ushort*)(base + 58*MB);
  ushort* WeTh = (ushort*)(base + 60*MB);
  ushort* WeTl = (ushort*)(base + 62*MB);
  ushort* WvTh = (ushort*)(base + 64*MB);
  ushort* WvTl = (ushort*)(base + 66*MB);
  ushort* WrTh = (ushort*)(base + 68*MB);
  ushort* WrTl = (ushort*)(base + 70*MB);
  ushort* Woh  = (ushort*)(base + 72*MB);
  ushort* Wol  = (ushort*)(base + 74*MB);

  // ---- all preprocessing in ONE launch (splits / transposes / R table) ----
  pre_k<<<dim3(1024, 8), dim3(256), 0, stream>>>(
      X, Y, Wo, Wq, We, Wv, Wr,
      Xh, Xl, Yh, Yl, Woh, Wol,
      WqTh, WqTl, WeTh, WeTl, WvTh, WvTl, WrTh, WrTl,
      Rh, Rl);

  // ---- fused q/k/v/Qm projections on MFMA ----
  gemm4_k<<<dim3(8, 16, 4), dim3(256), 0, stream>>>(
      Xh, Xl, Yh, Yl, Rh, Rl,
      WqTh, WqTl, WeTh, WeTl, WvTh, WvTl, WrTh, WrTl,
      qb, kb, vb, Qm);

  // ---- fused attention (role-split MFMA flash) ----
  attn_k<<<dim3(1024), dim3(256), 0, stream>>>(qb, kb, vb, Qm, cb, pb, Ob);

  // ---- out-projection on MFMA (+bias +residual), then LayerNorm ----
  split_swz_k<<<dim3(1024), dim3(256), 0, stream>>>(Ob, Oh, Ol, 2048);
  gemm_epi_k<<<dim3(8, 16), dim3(256), 0, stream>>>(Oh, Ol, Woh, Wol, Zb, Wob, X);
  ln_k<<<dim3(2048), dim3(256), 0, stream>>>(Zb, lng, lnb, out);
}